// Round 9
// baseline (70.525 us; speedup 1.0000x reference)
//
#include <hip/hip_runtime.h>
#include <hip/hip_bf16.h>
#include <hip/hip_fp16.h>

// GAT on MI355X. N=4096, DIN=512, H=128, K=4 heads, DOUT=16, p(adj)=0.01.
// D1 k_mask:  adj -> bitmask (pure streaming).
// D2 k_gemm1: X@W1 MFMA (64x128 tiles), fused src1/dst1 epilogue.
// D3 k_attn1: BARRIER-FREE, one wave per row: decode -> 4-head logits ->
//             f16 weights -> full-row 16B/lane gather -> ELU -> proj.
// D4 k_attn2: fused decode+logits -> attn + log_softmax (one wave per row).

typedef __attribute__((ext_vector_type(4))) float floatx4;
typedef __attribute__((ext_vector_type(8))) short short8;
typedef __attribute__((ext_vector_type(4))) unsigned short ushortx4;
typedef __attribute__((ext_vector_type(4))) unsigned int uintx4;
typedef unsigned short u16b;

#define GN 4096
#define LDP 40

__device__ __forceinline__ u16b f2bf(float f) {
  union { float f; unsigned int i; } v; v.f = f;
  unsigned int r = v.i + 0x7FFF + ((v.i >> 16) & 1);
  return (u16b)(r >> 16);
}
__device__ __forceinline__ float bflo(unsigned u) {
  union { unsigned i; float f; } v; v.i = u << 16; return v.f;
}
__device__ __forceinline__ float bfhi(unsigned u) {
  union { unsigned i; float f; } v; v.i = u & 0xffff0000u; return v.f;
}

// ---- D1: adj -> bitmask. 2 rows/block, 16 cols/thread.
__global__ __launch_bounds__(512) void k_mask(const float* __restrict__ adj,
                                              u16b* __restrict__ mask) {
  int t = threadIdx.x;
  int n = blockIdx.x * 2 + (t >> 8);
  int cg = t & 255;
  const float* ap = adj + (size_t)n * 4096 + cg * 16;
  floatx4 v0 = *(const floatx4*)(ap);
  floatx4 v1 = *(const floatx4*)(ap + 4);
  floatx4 v2 = *(const floatx4*)(ap + 8);
  floatx4 v3 = *(const floatx4*)(ap + 12);
  unsigned bits = 0;
#pragma unroll
  for (int i = 0; i < 4; ++i) {
    bits |= (unsigned)(v0[i] != 0.f) << i;
    bits |= (unsigned)(v1[i] != 0.f) << (4 + i);
    bits |= (unsigned)(v2[i] != 0.f) << (8 + i);
    bits |= (unsigned)(v3[i] != 0.f) << (12 + i);
  }
  if ((n >> 4) == cg) bits |= 1u << (n & 15);
  mask[(size_t)n * 256 + cg] = (u16b)bits;
}

// ---- D2: gemm1. 64x128 tile (row-panel x head), fused src1/dst1.
__global__ __launch_bounds__(512) void k_gemm1(const float* __restrict__ X,
    const float* __restrict__ W1, const float* __restrict__ as1,
    const float* __restrict__ ad1, u16b* __restrict__ Wh1bf,
    float* __restrict__ src1t, float* __restrict__ dst1t) {
  int b = blockIdx.x, t = threadIdx.x;
  int lane = t & 63, w = t >> 6;
  __shared__ u16b Ab[64 * LDP];
  __shared__ u16b Bb[128 * LDP];
  __shared__ float sps[4][64], sds[4][64];
  int p = ((b >> 5) << 3) | (b & 7);
  int hd = (b >> 3) & 3;
  int rb = p * 64;
  const float* Wk = W1 + (size_t)hd * 65536;
  int wr = w >> 2, wc = w & 3, lh = lane >> 4, lm = lane & 15;
  int ar = t >> 2, aq = t & 3;
  int u = t - 256, kk0 = (u & 7) * 4, c0 = (u >> 3) * 4;
  floatx4 pa0, pa1, pb0, pb1, pb2, pb3;
  if (t < 256) {
    const float* ap = X + (size_t)(rb + ar) * 512 + aq * 8;
    pa0 = *(const floatx4*)(ap);
    pa1 = *(const floatx4*)(ap + 4);
  } else {
    const float* bp = Wk + (size_t)kk0 * 128 + c0;
    pb0 = *(const floatx4*)(bp);
    pb1 = *(const floatx4*)(bp + 128);
    pb2 = *(const floatx4*)(bp + 256);
    pb3 = *(const floatx4*)(bp + 384);
  }
  floatx4 acc[2][2] = {};
  for (int kk = 0; kk < 512; kk += 32) {
    if (t < 256) {
      short8 a;
      a[0] = (short)f2bf(pa0[0]); a[1] = (short)f2bf(pa0[1]);
      a[2] = (short)f2bf(pa0[2]); a[3] = (short)f2bf(pa0[3]);
      a[4] = (short)f2bf(pa1[0]); a[5] = (short)f2bf(pa1[1]);
      a[6] = (short)f2bf(pa1[2]); a[7] = (short)f2bf(pa1[3]);
      *(short8*)(&Ab[ar * LDP + aq * 8]) = a;
    } else {
#pragma unroll
      for (int cq = 0; cq < 4; ++cq) {
        ushortx4 v;
        v[0] = f2bf(pb0[cq]); v[1] = f2bf(pb1[cq]);
        v[2] = f2bf(pb2[cq]); v[3] = f2bf(pb3[cq]);
        *(ushortx4*)(&Bb[(c0 + cq) * LDP + kk0]) = v;
      }
    }
    __syncthreads();
    if (kk + 32 < 512) {
      if (t < 256) {
        const float* ap = X + (size_t)(rb + ar) * 512 + kk + 32 + aq * 8;
        pa0 = *(const floatx4*)(ap);
        pa1 = *(const floatx4*)(ap + 4);
      } else {
        const float* bp = Wk + (size_t)(kk + 32 + kk0) * 128 + c0;
        pb0 = *(const floatx4*)(bp);
        pb1 = *(const floatx4*)(bp + 128);
        pb2 = *(const floatx4*)(bp + 256);
        pb3 = *(const floatx4*)(bp + 384);
      }
    }
    short8 a0 = *(const short8*)(&Ab[(wr * 32      + lm) * LDP + lh * 8]);
    short8 a1 = *(const short8*)(&Ab[(wr * 32 + 16 + lm) * LDP + lh * 8]);
    short8 b0 = *(const short8*)(&Bb[(wc * 32      + lm) * LDP + lh * 8]);
    short8 b1 = *(const short8*)(&Bb[(wc * 32 + 16 + lm) * LDP + lh * 8]);
    acc[0][0] = __builtin_amdgcn_mfma_f32_16x16x32_bf16(a0, b0, acc[0][0], 0, 0, 0);
    acc[0][1] = __builtin_amdgcn_mfma_f32_16x16x32_bf16(a0, b1, acc[0][1], 0, 0, 0);
    acc[1][0] = __builtin_amdgcn_mfma_f32_16x16x32_bf16(a1, b0, acc[1][0], 0, 0, 0);
    acc[1][1] = __builtin_amdgcn_mfma_f32_16x16x32_bf16(a1, b1, acc[1][1], 0, 0, 0);
    __syncthreads();
  }
#pragma unroll
  for (int m = 0; m < 2; ++m)
#pragma unroll
    for (int n2 = 0; n2 < 2; ++n2)
#pragma unroll
      for (int j = 0; j < 4; ++j)
        Wh1bf[(size_t)(rb + wr * 32 + m * 16 + lh * 4 + j) * 512
              + hd * 128 + wc * 32 + n2 * 16 + lm] = f2bf(acc[m][n2][j]);
  float asv[2], adv[2];
#pragma unroll
  for (int n2 = 0; n2 < 2; ++n2) {
    asv[n2] = as1[hd * 128 + wc * 32 + n2 * 16 + lm];
    adv[n2] = ad1[hd * 128 + wc * 32 + n2 * 16 + lm];
  }
#pragma unroll
  for (int m = 0; m < 2; ++m)
#pragma unroll
    for (int j = 0; j < 4; ++j) {
      float ps = acc[m][0][j] * asv[0] + acc[m][1][j] * asv[1];
      float pd = acc[m][0][j] * adv[0] + acc[m][1][j] * adv[1];
#pragma unroll
      for (int off = 8; off >= 1; off >>= 1) {
        ps += __shfl_xor(ps, off, 16);
        pd += __shfl_xor(pd, off, 16);
      }
      if (lm == 0) {
        sps[wc][wr * 32 + m * 16 + lh * 4 + j] = ps;
        sds[wc][wr * 32 + m * 16 + lh * 4 + j] = pd;
      }
    }
  __syncthreads();
  if (t < 64) {
    src1t[(size_t)(rb + t) * 4 + hd] = sps[0][t] + sps[1][t] + sps[2][t] + sps[3][t];
    dst1t[(size_t)(rb + t) * 4 + hd] = sds[0][t] + sds[1][t] + sds[2][t] + sds[3][t];
  }
}

// ---- D3: barrier-free attn1. One WAVE per row (4 rows/block, wave-local LDS).
__global__ __launch_bounds__(256) void k_attn1(const u16b* __restrict__ mask,
    const u16b* __restrict__ Wh1bf,
    const float* __restrict__ src1t, const float* __restrict__ dst1t,
    const float* __restrict__ W2, const float* __restrict__ as2,
    const float* __restrict__ ad2, float* __restrict__ Wh2,
    float* __restrict__ src2, float* __restrict__ dst2) {
  int w = threadIdx.x >> 6, lane = threadIdx.x & 63;
  int n = blockIdx.x * 4 + w;
  __shared__ u16b lst4[4][512];
  __shared__ unsigned short ewh4[4][2048];     // f16 weights [li][head]
  __shared__ float h1w4[4][512];
  u16b* lst = lst4[w];
  unsigned short* ewh = ewh4[w];
  float* h1w = h1w4[w];
  // ---- decode: lane l owns cols [64l, 64l+64)
  unsigned long long B = *(const unsigned long long*)((const char*)mask + (size_t)n * 512 + lane * 8);
  int pc = __popcll(B);
  int incl = pc;
#pragma unroll
  for (int off = 1; off <= 32; off <<= 1) {
    int v = __shfl_up(incl, off);
    if (lane >= off) incl += v;
  }
  int cnt = __shfl(incl, 63);
  int pos = incl - pc;
  while (B) {
    int c = __builtin_ctzll(B);
    lst[pos++] = (u16b)(lane * 64 + c);
    B &= B - 1;
  }
  // ---- logits for all 4 heads, online softmax in registers
  floatx4 sn = *(const floatx4*)(src1t + (size_t)n * 4);
  float mx[4], sm[4];
#pragma unroll
  for (int k = 0; k < 4; ++k) { mx[k] = -1e30f; sm[k] = 0.f; }
  for (int li = lane; li < cnt; li += 64) {
    int m = lst[li];
    floatx4 dv = *(const floatx4*)(dst1t + (size_t)m * 4);
    ushortx4 ev;
#pragma unroll
    for (int k = 0; k < 4; ++k) {
      float e = sn[k] + dv[k];
      e = e > 0.f ? e : 0.2f * e;
      ev[k] = __half_as_ushort(__float2half(e));
      if (e > mx[k]) { sm[k] = sm[k] * __expf(mx[k] - e) + 1.f; mx[k] = e; }
      else sm[k] += __expf(e - mx[k]);
    }
    *(ushortx4*)(&ewh[li * 4]) = ev;
  }
#pragma unroll
  for (int k = 0; k < 4; ++k) {
#pragma unroll
    for (int off = 32; off >= 1; off >>= 1) {
      float mo = __shfl_xor(mx[k], off);
      float so = __shfl_xor(sm[k], off);
      float M = fmaxf(mx[k], mo);
      sm[k] = sm[k] * __expf(mx[k] - M) + so * __expf(mo - M);
      mx[k] = M;
    }
    sm[k] = 1.f / sm[k];
  }
  // ---- normalize weights in place (f16)
  for (int li = lane; li < cnt; li += 64) {
    ushortx4 ev = *(const ushortx4*)(&ewh[li * 4]);
#pragma unroll
    for (int k = 0; k < 4; ++k) {
      float e = __half2float(__ushort_as_half(ev[k]));
      ev[k] = __half_as_ushort(__float2half(__expf(e - mx[k]) * sm[k]));
    }
    *(ushortx4*)(&ewh[li * 4]) = ev;
  }
  // ---- gather: whole 1KB row per iteration, lane covers cols [8l, 8l+8)
  int hd = lane >> 4;
  const char* gb = (const char*)Wh1bf + lane * 16;
  float a[8] = {0.f, 0.f, 0.f, 0.f, 0.f, 0.f, 0.f, 0.f};
#pragma unroll 2
  for (int li = 0; li < cnt; ++li) {
    int m = lst[li];
    float wv = __half2float(__ushort_as_half(ewh[li * 4 + hd]));
    uintx4 u = *(const uintx4*)(gb + (size_t)m * 1024);
    a[0] = fmaf(wv, bflo(u[0]), a[0]); a[1] = fmaf(wv, bfhi(u[0]), a[1]);
    a[2] = fmaf(wv, bflo(u[1]), a[2]); a[3] = fmaf(wv, bfhi(u[1]), a[3]);
    a[4] = fmaf(wv, bflo(u[2]), a[4]); a[5] = fmaf(wv, bfhi(u[2]), a[5]);
    a[6] = fmaf(wv, bflo(u[3]), a[6]); a[7] = fmaf(wv, bfhi(u[3]), a[7]);
  }
#pragma unroll
  for (int j = 0; j < 8; ++j) {
    float v = a[j];
    h1w[lane * 8 + j] = v > 0.f ? v : __expf(v) - 1.f;   // ELU
  }
  // ---- projection: out[o] = sum_i h1[i]*W2[i][o]; lane = (ig,o), i = ig + 4j
  int o = lane & 15, ig = lane >> 4;
  float p0 = 0.f, p1 = 0.f, p2 = 0.f, p3 = 0.f;
  for (int j = 0; j < 128; j += 4) {
    int i0 = ig + 4 * j;
    p0 = fmaf(h1w[i0],      W2[i0 * 16 + o],        p0);
    p1 = fmaf(h1w[i0 + 4],  W2[(i0 + 4) * 16 + o],  p1);
    p2 = fmaf(h1w[i0 + 8],  W2[(i0 + 8) * 16 + o],  p2);
    p3 = fmaf(h1w[i0 + 12], W2[(i0 + 12) * 16 + o], p3);
  }
  float pacc = (p0 + p1) + (p2 + p3);
  pacc += __shfl_xor(pacc, 16);
  pacc += __shfl_xor(pacc, 32);
  if (lane < 16) {
    Wh2[(size_t)n * 16 + lane] = pacc;
    float ps = pacc * as2[lane];
    float pd = pacc * ad2[lane];
#pragma unroll
    for (int off = 8; off >= 1; off >>= 1) {
      ps += __shfl_xor(ps, off, 16);
      pd += __shfl_xor(pd, off, 16);
    }
    if (lane == 0) { src2[n] = ps; dst2[n] = pd; }
  }
}

// ---- D4: fused decode+logits -> attn + log_softmax. One wave per row.
__global__ __launch_bounds__(256) void k_attn2(const u16b* __restrict__ mask,
    const float* __restrict__ Wh2, const float* __restrict__ src2,
    const float* __restrict__ dst2, float* __restrict__ out) {
  int w = threadIdx.x >> 6, lane = threadIdx.x & 63;
  int n = blockIdx.x * 4 + w;
  __shared__ int2 pr4[4][512];
  int2* pr = pr4[w];
  float snv = src2[n];
  unsigned long long B = *(const unsigned long long*)((const char*)mask + (size_t)n * 512 + lane * 8);
  int pc = __popcll(B);
  int incl = pc;
#pragma unroll
  for (int off = 1; off <= 32; off <<= 1) {
    int v = __shfl_up(incl, off);
    if (lane >= off) incl += v;
  }
  int cnt = __shfl(incl, 63);
  int pos = incl - pc;
  float mx = -1e30f, sm = 0.f;
  while (B) {
    int c = __builtin_ctzll(B);
    int m = lane * 64 + c;
    float e = snv + dst2[m];
    e = e > 0.f ? e : 0.2f * e;
    if (e > mx) { sm = sm * __expf(mx - e) + 1.f; mx = e; }
    else sm += __expf(e - mx);
    int2 pv; pv.x = m << 4; pv.y = __float_as_int(e);
    pr[pos++] = pv;
    B &= B - 1;
  }
#pragma unroll
  for (int off = 32; off >= 1; off >>= 1) {
    float mo = __shfl_xor(mx, off);
    float so = __shfl_xor(sm, off);
    float M = fmaxf(mx, mo);
    sm = sm * __expf(mx - M) + so * __expf(mo - M);
    mx = M;
  }
  float R = 1.f / sm;
  int o = lane & 15, g = lane >> 4;
  float acc = 0.f;
  for (int li = g; li < cnt; li += 4) {
    int2 pv = pr[li];
    float wgt = __expf(__int_as_float(pv.y) - mx) * R;
    acc = fmaf(wgt, Wh2[pv.x + o], acc);
  }
  acc += __shfl_xor(acc, 16);
  acc += __shfl_xor(acc, 32);
  float vm = acc;
#pragma unroll
  for (int off = 8; off >= 1; off >>= 1) vm = fmaxf(vm, __shfl_xor(vm, off, 16));
  float ex = __expf(acc - vm);
#pragma unroll
  for (int off = 8; off >= 1; off >>= 1) ex += __shfl_xor(ex, off, 16);
  if (lane < 16) out[(size_t)n * 16 + lane] = acc - vm - __logf(ex);
}

extern "C" void kernel_launch(void* const* d_in, const int* in_sizes, int n_in,
                              void* d_out, int out_size, void* d_ws, size_t ws_size,
                              hipStream_t stream) {
  const float* X   = (const float*)d_in[0];
  const float* adj = (const float*)d_in[1];
  const float* W1  = (const float*)d_in[2];
  const float* as1 = (const float*)d_in[3];
  const float* ad1 = (const float*)d_in[4];
  const float* W2  = (const float*)d_in[5];
  const float* as2 = (const float*)d_in[6];
  const float* ad2 = (const float*)d_in[7];
  float* out = (float*)d_out;

  char* ws = (char*)d_ws;
  float* src1t = (float*)ws;                         // 64 KB  [n][k]
  float* dst1t = (float*)(ws + (64 << 10));          // 64 KB  [n][k]
  float* src2  = (float*)(ws + (128 << 10));         // 16 KB
  float* dst2  = (float*)(ws + (144 << 10));         // 16 KB
  float* Wh2   = (float*)(ws + (160 << 10));         // 256 KB
  u16b*  mask  = (u16b*)(ws + (512 << 10));          // 2 MB
  u16b*  Wh1bf = (u16b*)(ws + (4ull << 20));         // 4 MB

  k_mask <<<dim3(2048), dim3(512), 0, stream>>>(adj, mask);
  k_gemm1<<<dim3(256),  dim3(512), 0, stream>>>(X, W1, as1, ad1, Wh1bf, src1t, dst1t);
  k_attn1<<<dim3(1024), dim3(256), 0, stream>>>(mask, Wh1bf, src1t, dst1t,
                                                W2, as2, ad2, Wh2, src2, dst2);
  k_attn2<<<dim3(1024), dim3(256), 0, stream>>>(mask, Wh2, src2, dst2, out);
}

// Round 10
// 61.626 us; speedup vs baseline: 1.1444x; 1.1444x over previous
//
#include <hip/hip_runtime.h>
#include <hip/hip_bf16.h>
#include <hip/hip_fp16.h>

// GAT on MI355X. N=4096, DIN=512, H=128, K=4 heads, DOUT=16, p(adj)=0.01.
// D1 k_mask:  adj -> bitmask (streaming).
// D2 k_gemm1: X@W1 MFMA (64x128 tiles), fused src1/dst1 epilogue.
// D3 k_attn1: one wave/row; 8-batched gather (8 loads in flight), transposed
//             h1 LDS (bank-conflict-free), fused layer-2 projection.
// D4 k_attn2: fused decode+logits -> attn + log_softmax (one wave per row).

typedef __attribute__((ext_vector_type(4))) float floatx4;
typedef __attribute__((ext_vector_type(8))) short short8;
typedef __attribute__((ext_vector_type(4))) unsigned short ushortx4;
typedef __attribute__((ext_vector_type(4))) unsigned int uintx4;
typedef unsigned short u16b;

#define GN 4096
#define LDP 40

__device__ __forceinline__ u16b f2bf(float f) {
  union { float f; unsigned int i; } v; v.f = f;
  unsigned int r = v.i + 0x7FFF + ((v.i >> 16) & 1);
  return (u16b)(r >> 16);
}
__device__ __forceinline__ float bflo(unsigned u) {
  union { unsigned i; float f; } v; v.i = u << 16; return v.f;
}
__device__ __forceinline__ float bfhi(unsigned u) {
  union { unsigned i; float f; } v; v.i = u & 0xffff0000u; return v.f;
}
__device__ __forceinline__ float h2f(unsigned short h) {
  return __half2float(__ushort_as_half(h));
}

// ---- D1: adj -> bitmask. 2 rows/block, 16 cols/thread.
__global__ __launch_bounds__(512) void k_mask(const float* __restrict__ adj,
                                              u16b* __restrict__ mask) {
  int t = threadIdx.x;
  int n = blockIdx.x * 2 + (t >> 8);
  int cg = t & 255;
  const float* ap = adj + (size_t)n * 4096 + cg * 16;
  floatx4 v0 = *(const floatx4*)(ap);
  floatx4 v1 = *(const floatx4*)(ap + 4);
  floatx4 v2 = *(const floatx4*)(ap + 8);
  floatx4 v3 = *(const floatx4*)(ap + 12);
  unsigned bits = 0;
#pragma unroll
  for (int i = 0; i < 4; ++i) {
    bits |= (unsigned)(v0[i] != 0.f) << i;
    bits |= (unsigned)(v1[i] != 0.f) << (4 + i);
    bits |= (unsigned)(v2[i] != 0.f) << (8 + i);
    bits |= (unsigned)(v3[i] != 0.f) << (12 + i);
  }
  if ((n >> 4) == cg) bits |= 1u << (n & 15);
  mask[(size_t)n * 256 + cg] = (u16b)bits;
}

// ---- D2: gemm1. 64x128 tile (row-panel x head), fused src1/dst1. (unchanged)
__global__ __launch_bounds__(512) void k_gemm1(const float* __restrict__ X,
    const float* __restrict__ W1, const float* __restrict__ as1,
    const float* __restrict__ ad1, u16b* __restrict__ Wh1bf,
    float* __restrict__ src1t, float* __restrict__ dst1t) {
  int b = blockIdx.x, t = threadIdx.x;
  int lane = t & 63, w = t >> 6;
  __shared__ u16b Ab[64 * LDP];
  __shared__ u16b Bb[128 * LDP];
  __shared__ float sps[4][64], sds[4][64];
  int p = ((b >> 5) << 3) | (b & 7);
  int hd = (b >> 3) & 3;
  int rb = p * 64;
  const float* Wk = W1 + (size_t)hd * 65536;
  int wr = w >> 2, wc = w & 3, lh = lane >> 4, lm = lane & 15;
  int ar = t >> 2, aq = t & 3;
  int u = t - 256, kk0 = (u & 7) * 4, c0 = (u >> 3) * 4;
  floatx4 pa0, pa1, pb0, pb1, pb2, pb3;
  if (t < 256) {
    const float* ap = X + (size_t)(rb + ar) * 512 + aq * 8;
    pa0 = *(const floatx4*)(ap);
    pa1 = *(const floatx4*)(ap + 4);
  } else {
    const float* bp = Wk + (size_t)kk0 * 128 + c0;
    pb0 = *(const floatx4*)(bp);
    pb1 = *(const floatx4*)(bp + 128);
    pb2 = *(const floatx4*)(bp + 256);
    pb3 = *(const floatx4*)(bp + 384);
  }
  floatx4 acc[2][2] = {};
  for (int kk = 0; kk < 512; kk += 32) {
    if (t < 256) {
      short8 a;
      a[0] = (short)f2bf(pa0[0]); a[1] = (short)f2bf(pa0[1]);
      a[2] = (short)f2bf(pa0[2]); a[3] = (short)f2bf(pa0[3]);
      a[4] = (short)f2bf(pa1[0]); a[5] = (short)f2bf(pa1[1]);
      a[6] = (short)f2bf(pa1[2]); a[7] = (short)f2bf(pa1[3]);
      *(short8*)(&Ab[ar * LDP + aq * 8]) = a;
    } else {
#pragma unroll
      for (int cq = 0; cq < 4; ++cq) {
        ushortx4 v;
        v[0] = f2bf(pb0[cq]); v[1] = f2bf(pb1[cq]);
        v[2] = f2bf(pb2[cq]); v[3] = f2bf(pb3[cq]);
        *(ushortx4*)(&Bb[(c0 + cq) * LDP + kk0]) = v;
      }
    }
    __syncthreads();
    if (kk + 32 < 512) {
      if (t < 256) {
        const float* ap = X + (size_t)(rb + ar) * 512 + kk + 32 + aq * 8;
        pa0 = *(const floatx4*)(ap);
        pa1 = *(const floatx4*)(ap + 4);
      } else {
        const float* bp = Wk + (size_t)(kk + 32 + kk0) * 128 + c0;
        pb0 = *(const floatx4*)(bp);
        pb1 = *(const floatx4*)(bp + 128);
        pb2 = *(const floatx4*)(bp + 256);
        pb3 = *(const floatx4*)(bp + 384);
      }
    }
    short8 a0 = *(const short8*)(&Ab[(wr * 32      + lm) * LDP + lh * 8]);
    short8 a1 = *(const short8*)(&Ab[(wr * 32 + 16 + lm) * LDP + lh * 8]);
    short8 b0 = *(const short8*)(&Bb[(wc * 32      + lm) * LDP + lh * 8]);
    short8 b1 = *(const short8*)(&Bb[(wc * 32 + 16 + lm) * LDP + lh * 8]);
    acc[0][0] = __builtin_amdgcn_mfma_f32_16x16x32_bf16(a0, b0, acc[0][0], 0, 0, 0);
    acc[0][1] = __builtin_amdgcn_mfma_f32_16x16x32_bf16(a0, b1, acc[0][1], 0, 0, 0);
    acc[1][0] = __builtin_amdgcn_mfma_f32_16x16x32_bf16(a1, b0, acc[1][0], 0, 0, 0);
    acc[1][1] = __builtin_amdgcn_mfma_f32_16x16x32_bf16(a1, b1, acc[1][1], 0, 0, 0);
    __syncthreads();
  }
#pragma unroll
  for (int m = 0; m < 2; ++m)
#pragma unroll
    for (int n2 = 0; n2 < 2; ++n2)
#pragma unroll
      for (int j = 0; j < 4; ++j)
        Wh1bf[(size_t)(rb + wr * 32 + m * 16 + lh * 4 + j) * 512
              + hd * 128 + wc * 32 + n2 * 16 + lm] = f2bf(acc[m][n2][j]);
  float asv[2], adv[2];
#pragma unroll
  for (int n2 = 0; n2 < 2; ++n2) {
    asv[n2] = as1[hd * 128 + wc * 32 + n2 * 16 + lm];
    adv[n2] = ad1[hd * 128 + wc * 32 + n2 * 16 + lm];
  }
#pragma unroll
  for (int m = 0; m < 2; ++m)
#pragma unroll
    for (int j = 0; j < 4; ++j) {
      float ps = acc[m][0][j] * asv[0] + acc[m][1][j] * asv[1];
      float pd = acc[m][0][j] * adv[0] + acc[m][1][j] * adv[1];
#pragma unroll
      for (int off = 8; off >= 1; off >>= 1) {
        ps += __shfl_xor(ps, off, 16);
        pd += __shfl_xor(pd, off, 16);
      }
      if (lm == 0) {
        sps[wc][wr * 32 + m * 16 + lh * 4 + j] = ps;
        sds[wc][wr * 32 + m * 16 + lh * 4 + j] = pd;
      }
    }
  __syncthreads();
  if (t < 64) {
    src1t[(size_t)(rb + t) * 4 + hd] = sps[0][t] + sps[1][t] + sps[2][t] + sps[3][t];
    dst1t[(size_t)(rb + t) * 4 + hd] = sds[0][t] + sds[1][t] + sds[2][t] + sds[3][t];
  }
}

// ---- D3: attn1. One wave/row; 8-batched deep-pipelined gather.
__global__ __launch_bounds__(256) void k_attn1(const u16b* __restrict__ mask,
    const u16b* __restrict__ Wh1bf,
    const float* __restrict__ src1t, const float* __restrict__ dst1t,
    const float* __restrict__ W2, const float* __restrict__ as2,
    const float* __restrict__ ad2, float* __restrict__ Wh2,
    float* __restrict__ src2, float* __restrict__ dst2) {
  int w = threadIdx.x >> 6, lane = threadIdx.x & 63;
  int n = blockIdx.x * 4 + w;
  __shared__ u16b lst4[4][512];
  __shared__ unsigned short ewh4[4][2048];     // f16 normalized weights [li*4+k]
  __shared__ float h1t4[4][512];               // transposed: [(col&7)*64 + col>>3]
  u16b* lst = lst4[w];
  unsigned short* ewh = ewh4[w];
  float* h1t = h1t4[w];
  // ---- decode: lane l owns cols [64l, 64l+64)
  unsigned long long B = *(const unsigned long long*)((const char*)mask + (size_t)n * 512 + lane * 8);
  int pc = __popcll(B);
  int incl = pc;
#pragma unroll
  for (int off = 1; off <= 32; off <<= 1) {
    int v = __shfl_up(incl, off);
    if (lane >= off) incl += v;
  }
  int cnt = __shfl(incl, 63);
  int pos = incl - pc;
  while (B) {
    int c = __builtin_ctzll(B);
    lst[pos++] = (u16b)(lane * 64 + c);
    B &= B - 1;
  }
  // ---- logits all 4 heads, online softmax in registers
  floatx4 sn = *(const floatx4*)(src1t + (size_t)n * 4);
  float mx[4], sm[4];
#pragma unroll
  for (int k = 0; k < 4; ++k) { mx[k] = -1e30f; sm[k] = 0.f; }
  for (int li = lane; li < cnt; li += 64) {
    int m = lst[li];
    floatx4 dv = *(const floatx4*)(dst1t + (size_t)m * 4);
    ushortx4 ev;
#pragma unroll
    for (int k = 0; k < 4; ++k) {
      float e = sn[k] + dv[k];
      e = e > 0.f ? e : 0.2f * e;
      ev[k] = __half_as_ushort(__float2half(e));
      if (e > mx[k]) { sm[k] = sm[k] * __expf(mx[k] - e) + 1.f; mx[k] = e; }
      else sm[k] += __expf(e - mx[k]);
    }
    *(ushortx4*)(&ewh[li * 4]) = ev;
  }
#pragma unroll
  for (int k = 0; k < 4; ++k) {
#pragma unroll
    for (int off = 32; off >= 1; off >>= 1) {
      float mo = __shfl_xor(mx[k], off);
      float so = __shfl_xor(sm[k], off);
      float M = fmaxf(mx[k], mo);
      sm[k] = sm[k] * __expf(mx[k] - M) + so * __expf(mo - M);
      mx[k] = M;
    }
    sm[k] = 1.f / sm[k];
  }
  for (int li = lane; li < cnt; li += 64) {
    ushortx4 ev = *(const ushortx4*)(&ewh[li * 4]);
#pragma unroll
    for (int k = 0; k < 4; ++k) {
      float e = h2f(ev[k]);
      ev[k] = __half_as_ushort(__float2half(__expf(e - mx[k]) * sm[k]));
    }
    *(ushortx4*)(&ewh[li * 4]) = ev;
  }
  // ---- gather, 8-batched: 8 independent 16B loads in flight per wave.
  int hd = lane >> 4;
  const char* gb = (const char*)Wh1bf + lane * 16;
  float a[8] = {0.f, 0.f, 0.f, 0.f, 0.f, 0.f, 0.f, 0.f};
  int mreg[8];
  float wreg[8];
  int nfull = cnt >> 3;
  if (nfull) {
#pragma unroll
    for (int q = 0; q < 8; ++q) {
      mreg[q] = lst[q];
      wreg[q] = h2f(ewh[q * 4 + hd]);
    }
  }
  for (int c = 0; c < nfull; ++c) {
    // issue all 8 loads (addresses already in regs)
    uintx4 u0 = *(const uintx4*)(gb + (size_t)mreg[0] * 1024);
    uintx4 u1 = *(const uintx4*)(gb + (size_t)mreg[1] * 1024);
    uintx4 u2 = *(const uintx4*)(gb + (size_t)mreg[2] * 1024);
    uintx4 u3 = *(const uintx4*)(gb + (size_t)mreg[3] * 1024);
    uintx4 u4 = *(const uintx4*)(gb + (size_t)mreg[4] * 1024);
    uintx4 u5 = *(const uintx4*)(gb + (size_t)mreg[5] * 1024);
    uintx4 u6 = *(const uintx4*)(gb + (size_t)mreg[6] * 1024);
    uintx4 u7 = *(const uintx4*)(gb + (size_t)mreg[7] * 1024);
    float f0 = wreg[0], f1 = wreg[1], f2 = wreg[2], f3 = wreg[3];
    float f4 = wreg[4], f5 = wreg[5], f6 = wreg[6], f7 = wreg[7];
    if (c + 1 < nfull) {                       // prefetch next chunk's metadata
      int nb = (c + 1) * 8;
#pragma unroll
      for (int q = 0; q < 8; ++q) {
        mreg[q] = lst[nb + q];
        wreg[q] = h2f(ewh[(nb + q) * 4 + hd]);
      }
    }
#pragma unroll
    for (int j = 0; j < 4; ++j) {
      a[2*j]   = fmaf(f0, bflo(u0[j]), a[2*j]); a[2*j+1] = fmaf(f0, bfhi(u0[j]), a[2*j+1]);
    }
#pragma unroll
    for (int j = 0; j < 4; ++j) {
      a[2*j]   = fmaf(f1, bflo(u1[j]), a[2*j]); a[2*j+1] = fmaf(f1, bfhi(u1[j]), a[2*j+1]);
    }
#pragma unroll
    for (int j = 0; j < 4; ++j) {
      a[2*j]   = fmaf(f2, bflo(u2[j]), a[2*j]); a[2*j+1] = fmaf(f2, bfhi(u2[j]), a[2*j+1]);
    }
#pragma unroll
    for (int j = 0; j < 4; ++j) {
      a[2*j]   = fmaf(f3, bflo(u3[j]), a[2*j]); a[2*j+1] = fmaf(f3, bfhi(u3[j]), a[2*j+1]);
    }
#pragma unroll
    for (int j = 0; j < 4; ++j) {
      a[2*j]   = fmaf(f4, bflo(u4[j]), a[2*j]); a[2*j+1] = fmaf(f4, bfhi(u4[j]), a[2*j+1]);
    }
#pragma unroll
    for (int j = 0; j < 4; ++j) {
      a[2*j]   = fmaf(f5, bflo(u5[j]), a[2*j]); a[2*j+1] = fmaf(f5, bfhi(u5[j]), a[2*j+1]);
    }
#pragma unroll
    for (int j = 0; j < 4; ++j) {
      a[2*j]   = fmaf(f6, bflo(u6[j]), a[2*j]); a[2*j+1] = fmaf(f6, bfhi(u6[j]), a[2*j+1]);
    }
#pragma unroll
    for (int j = 0; j < 4; ++j) {
      a[2*j]   = fmaf(f7, bflo(u7[j]), a[2*j]); a[2*j+1] = fmaf(f7, bfhi(u7[j]), a[2*j+1]);
    }
  }
  for (int li = nfull * 8; li < cnt; ++li) {   // tail
    int m = lst[li];
    float wv = h2f(ewh[li * 4 + hd]);
    uintx4 u = *(const uintx4*)(gb + (size_t)m * 1024);
#pragma unroll
    for (int j = 0; j < 4; ++j) {
      a[2*j]   = fmaf(wv, bflo(u[j]), a[2*j]);
      a[2*j+1] = fmaf(wv, bfhi(u[j]), a[2*j+1]);
    }
  }
  // ---- ELU + transposed store: col = 8*lane + j -> h1t[j*64 + lane] (conflict-free)
#pragma unroll
  for (int j = 0; j < 8; ++j) {
    float v = a[j];
    h1t[j * 64 + lane] = v > 0.f ? v : __expf(v) - 1.f;
  }
  // ---- projection: out[o] = sum_i h1[i] W2[i][o]; i = ig + 4j; h1[i] = h1t[(i&7)*64+(i>>3)]
  int o = lane & 15, ig = lane >> 4;
  float p0 = 0.f, p1 = 0.f, p2 = 0.f, p3 = 0.f;
  for (int j = 0; j < 128; j += 4) {
    int i0 = ig + 4 * j;
    int i1 = i0 + 4, i2 = i0 + 8, i3 = i0 + 12;
    p0 = fmaf(h1t[(i0 & 7) * 64 + (i0 >> 3)], W2[i0 * 16 + o], p0);
    p1 = fmaf(h1t[(i1 & 7) * 64 + (i1 >> 3)], W2[i1 * 16 + o], p1);
    p2 = fmaf(h1t[(i2 & 7) * 64 + (i2 >> 3)], W2[i2 * 16 + o], p2);
    p3 = fmaf(h1t[(i3 & 7) * 64 + (i3 >> 3)], W2[i3 * 16 + o], p3);
  }
  float pacc = (p0 + p1) + (p2 + p3);
  pacc += __shfl_xor(pacc, 16);
  pacc += __shfl_xor(pacc, 32);
  if (lane < 16) {
    Wh2[(size_t)n * 16 + lane] = pacc;
    float ps = pacc * as2[lane];
    float pd = pacc * ad2[lane];
#pragma unroll
    for (int off = 8; off >= 1; off >>= 1) {
      ps += __shfl_xor(ps, off, 16);
      pd += __shfl_xor(pd, off, 16);
    }
    if (lane == 0) { src2[n] = ps; dst2[n] = pd; }
  }
}

// ---- D4: fused decode+logits -> attn + log_softmax. One wave per row.
__global__ __launch_bounds__(256) void k_attn2(const u16b* __restrict__ mask,
    const float* __restrict__ Wh2, const float* __restrict__ src2,
    const float* __restrict__ dst2, float* __restrict__ out) {
  int w = threadIdx.x >> 6, lane = threadIdx.x & 63;
  int n = blockIdx.x * 4 + w;
  __shared__ int2 pr4[4][512];
  int2* pr = pr4[w];
  float snv = src2[n];
  unsigned long long B = *(const unsigned long long*)((const char*)mask + (size_t)n * 512 + lane * 8);
  int pc = __popcll(B);
  int incl = pc;
#pragma unroll
  for (int off = 1; off <= 32; off <<= 1) {
    int v = __shfl_up(incl, off);
    if (lane >= off) incl += v;
  }
  int cnt = __shfl(incl, 63);
  int pos = incl - pc;
  float mx = -1e30f, sm = 0.f;
  while (B) {
    int c = __builtin_ctzll(B);
    int m = lane * 64 + c;
    float e = snv + dst2[m];
    e = e > 0.f ? e : 0.2f * e;
    if (e > mx) { sm = sm * __expf(mx - e) + 1.f; mx = e; }
    else sm += __expf(e - mx);
    int2 pv; pv.x = m << 4; pv.y = __float_as_int(e);
    pr[pos++] = pv;
    B &= B - 1;
  }
#pragma unroll
  for (int off = 32; off >= 1; off >>= 1) {
    float mo = __shfl_xor(mx, off);
    float so = __shfl_xor(sm, off);
    float M = fmaxf(mx, mo);
    sm = sm * __expf(mx - M) + so * __expf(mo - M);
    mx = M;
  }
  float R = 1.f / sm;
  int o = lane & 15, g = lane >> 4;
  float acc = 0.f;
  for (int li = g; li < cnt; li += 4) {
    int2 pv = pr[li];
    float wgt = __expf(__int_as_float(pv.y) - mx) * R;
    acc = fmaf(wgt, Wh2[pv.x + o], acc);
  }
  acc += __shfl_xor(acc, 16);
  acc += __shfl_xor(acc, 32);
  float vm = acc;
#pragma unroll
  for (int off = 8; off >= 1; off >>= 1) vm = fmaxf(vm, __shfl_xor(vm, off, 16));
  float ex = __expf(acc - vm);
#pragma unroll
  for (int off = 8; off >= 1; off >>= 1) ex += __shfl_xor(ex, off, 16);
  if (lane < 16) out[(size_t)n * 16 + lane] = acc - vm - __logf(ex);
}

extern "C" void kernel_launch(void* const* d_in, const int* in_sizes, int n_in,
                              void* d_out, int out_size, void* d_ws, size_t ws_size,
                              hipStream_t stream) {
  const float* X   = (const float*)d_in[0];
  const float* adj = (const float*)d_in[1];
  const float* W1  = (const float*)d_in[2];
  const float* as1 = (const float*)d_in[3];
  const float* ad1 = (const float*)d_in[4];
  const float* W2  = (const float*)d_in[5];
  const float* as2 = (const float*)d_in[6];
  const float* ad2 = (const float*)d_in[7];
  float* out = (float*)d_out;

  char* ws = (char*)d_ws;
  float* src1t = (float*)ws;                         // 64 KB
  float* dst1t = (float*)(ws + (64 << 10));          // 64 KB
  float* src2  = (float*)(ws + (128 << 10));         // 16 KB
  float* dst2  = (float*)(ws + (144 << 10));         // 16 KB
  float* Wh2   = (float*)(ws + (160 << 10));         // 256 KB
  u16b*  mask  = (u16b*)(ws + (512 << 10));          // 2 MB
  u16b*  Wh1bf = (u16b*)(ws + (4ull << 20));         // 4 MB

  k_mask <<<dim3(2048), dim3(512), 0, stream>>>(adj, mask);
  k_gemm1<<<dim3(256),  dim3(512), 0, stream>>>(X, W1, as1, ad1, Wh1bf, src1t, dst1t);
  k_attn1<<<dim3(1024), dim3(256), 0, stream>>>(mask, Wh1bf, src1t, dst1t,
                                                W2, as2, ad2, Wh2, src2, dst2);
  k_attn2<<<dim3(1024), dim3(256), 0, stream>>>(mask, Wh2, src2, dst2, out);
}

// Round 11
// 57.572 us; speedup vs baseline: 1.2250x; 1.0704x over previous
//
#include <hip/hip_runtime.h>
#include <hip/hip_bf16.h>
#include <hip/hip_fp16.h>

// GAT on MI355X. N=4096, DIN=512, H=128, K=4 heads, DOUT=16, p(adj)=0.01.
// D1 k_fused1: gemm1 (MFMA, blocks 0..255) || adj->bitmask (blocks 256..2303).
// D2 k_attn1:  one wave/row; 2-deep pipelined gather (16 loads in flight),
//              transposed h1 LDS, fused layer-2 projection.
// D3 k_attn2:  fused decode+logits -> attn + log_softmax (one wave per row).

typedef __attribute__((ext_vector_type(4))) float floatx4;
typedef __attribute__((ext_vector_type(8))) short short8;
typedef __attribute__((ext_vector_type(4))) unsigned short ushortx4;
typedef __attribute__((ext_vector_type(4))) unsigned int uintx4;
typedef unsigned short u16b;

#define GN 4096
#define LDP 40

__device__ __forceinline__ u16b f2bf(float f) {
  union { float f; unsigned int i; } v; v.f = f;
  unsigned int r = v.i + 0x7FFF + ((v.i >> 16) & 1);
  return (u16b)(r >> 16);
}
__device__ __forceinline__ float bflo(unsigned u) {
  union { unsigned i; float f; } v; v.i = u << 16; return v.f;
}
__device__ __forceinline__ float bfhi(unsigned u) {
  union { unsigned i; float f; } v; v.i = u & 0xffff0000u; return v.f;
}
__device__ __forceinline__ float h2f(unsigned short h) {
  return __half2float(__ushort_as_half(h));
}

// ---- D1: gemm1 (blocks 0..255) || bitmask build (blocks 256..2303).
__global__ __launch_bounds__(512) void k_fused1(const float* __restrict__ adj,
    const float* __restrict__ X, const float* __restrict__ W1,
    const float* __restrict__ as1, const float* __restrict__ ad1,
    u16b* __restrict__ mask, u16b* __restrict__ Wh1bf,
    float* __restrict__ src1t, float* __restrict__ dst1t) {
  int b = blockIdx.x, t = threadIdx.x;
  int lane = t & 63, w = t >> 6;
  if (b >= 256) {
    int n = (b - 256) * 2 + (t >> 8);
    int cg = t & 255;
    const float* ap = adj + (size_t)n * 4096 + cg * 16;
    floatx4 v0 = *(const floatx4*)(ap);
    floatx4 v1 = *(const floatx4*)(ap + 4);
    floatx4 v2 = *(const floatx4*)(ap + 8);
    floatx4 v3 = *(const floatx4*)(ap + 12);
    unsigned bits = 0;
#pragma unroll
    for (int i = 0; i < 4; ++i) {
      bits |= (unsigned)(v0[i] != 0.f) << i;
      bits |= (unsigned)(v1[i] != 0.f) << (4 + i);
      bits |= (unsigned)(v2[i] != 0.f) << (8 + i);
      bits |= (unsigned)(v3[i] != 0.f) << (12 + i);
    }
    if ((n >> 4) == cg) bits |= 1u << (n & 15);
    mask[(size_t)n * 256 + cg] = (u16b)bits;
  } else {
    __shared__ u16b Ab[64 * LDP];
    __shared__ u16b Bb[128 * LDP];
    __shared__ float sps[4][64], sds[4][64];
    int p = ((b >> 5) << 3) | (b & 7);
    int hd = (b >> 3) & 3;
    int rb = p * 64;
    const float* Wk = W1 + (size_t)hd * 65536;
    int wr = w >> 2, wc = w & 3, lh = lane >> 4, lm = lane & 15;
    int ar = t >> 2, aq = t & 3;
    int u = t - 256, kk0 = (u & 7) * 4, c0 = (u >> 3) * 4;
    floatx4 pa0, pa1, pb0, pb1, pb2, pb3;
    if (t < 256) {
      const float* ap = X + (size_t)(rb + ar) * 512 + aq * 8;
      pa0 = *(const floatx4*)(ap);
      pa1 = *(const floatx4*)(ap + 4);
    } else {
      const float* bp = Wk + (size_t)kk0 * 128 + c0;
      pb0 = *(const floatx4*)(bp);
      pb1 = *(const floatx4*)(bp + 128);
      pb2 = *(const floatx4*)(bp + 256);
      pb3 = *(const floatx4*)(bp + 384);
    }
    floatx4 acc[2][2] = {};
    for (int kk = 0; kk < 512; kk += 32) {
      if (t < 256) {
        short8 a;
        a[0] = (short)f2bf(pa0[0]); a[1] = (short)f2bf(pa0[1]);
        a[2] = (short)f2bf(pa0[2]); a[3] = (short)f2bf(pa0[3]);
        a[4] = (short)f2bf(pa1[0]); a[5] = (short)f2bf(pa1[1]);
        a[6] = (short)f2bf(pa1[2]); a[7] = (short)f2bf(pa1[3]);
        *(short8*)(&Ab[ar * LDP + aq * 8]) = a;
      } else {
#pragma unroll
        for (int cq = 0; cq < 4; ++cq) {
          ushortx4 v;
          v[0] = f2bf(pb0[cq]); v[1] = f2bf(pb1[cq]);
          v[2] = f2bf(pb2[cq]); v[3] = f2bf(pb3[cq]);
          *(ushortx4*)(&Bb[(c0 + cq) * LDP + kk0]) = v;
        }
      }
      __syncthreads();
      if (kk + 32 < 512) {
        if (t < 256) {
          const float* ap = X + (size_t)(rb + ar) * 512 + kk + 32 + aq * 8;
          pa0 = *(const floatx4*)(ap);
          pa1 = *(const floatx4*)(ap + 4);
        } else {
          const float* bp = Wk + (size_t)(kk + 32 + kk0) * 128 + c0;
          pb0 = *(const floatx4*)(bp);
          pb1 = *(const floatx4*)(bp + 128);
          pb2 = *(const floatx4*)(bp + 256);
          pb3 = *(const floatx4*)(bp + 384);
        }
      }
      short8 a0 = *(const short8*)(&Ab[(wr * 32      + lm) * LDP + lh * 8]);
      short8 a1 = *(const short8*)(&Ab[(wr * 32 + 16 + lm) * LDP + lh * 8]);
      short8 b0 = *(const short8*)(&Bb[(wc * 32      + lm) * LDP + lh * 8]);
      short8 b1 = *(const short8*)(&Bb[(wc * 32 + 16 + lm) * LDP + lh * 8]);
      acc[0][0] = __builtin_amdgcn_mfma_f32_16x16x32_bf16(a0, b0, acc[0][0], 0, 0, 0);
      acc[0][1] = __builtin_amdgcn_mfma_f32_16x16x32_bf16(a0, b1, acc[0][1], 0, 0, 0);
      acc[1][0] = __builtin_amdgcn_mfma_f32_16x16x32_bf16(a1, b0, acc[1][0], 0, 0, 0);
      acc[1][1] = __builtin_amdgcn_mfma_f32_16x16x32_bf16(a1, b1, acc[1][1], 0, 0, 0);
      __syncthreads();
    }
#pragma unroll
    for (int m = 0; m < 2; ++m)
#pragma unroll
      for (int n2 = 0; n2 < 2; ++n2)
#pragma unroll
        for (int j = 0; j < 4; ++j)
          Wh1bf[(size_t)(rb + wr * 32 + m * 16 + lh * 4 + j) * 512
                + hd * 128 + wc * 32 + n2 * 16 + lm] = f2bf(acc[m][n2][j]);
    float asv[2], adv[2];
#pragma unroll
    for (int n2 = 0; n2 < 2; ++n2) {
      asv[n2] = as1[hd * 128 + wc * 32 + n2 * 16 + lm];
      adv[n2] = ad1[hd * 128 + wc * 32 + n2 * 16 + lm];
    }
#pragma unroll
    for (int m = 0; m < 2; ++m)
#pragma unroll
      for (int j = 0; j < 4; ++j) {
        float ps = acc[m][0][j] * asv[0] + acc[m][1][j] * asv[1];
        float pd = acc[m][0][j] * adv[0] + acc[m][1][j] * adv[1];
#pragma unroll
        for (int off = 8; off >= 1; off >>= 1) {
          ps += __shfl_xor(ps, off, 16);
          pd += __shfl_xor(pd, off, 16);
        }
        if (lm == 0) {
          sps[wc][wr * 32 + m * 16 + lh * 4 + j] = ps;
          sds[wc][wr * 32 + m * 16 + lh * 4 + j] = pd;
        }
      }
    __syncthreads();
    if (t < 64) {
      src1t[(size_t)(rb + t) * 4 + hd] = sps[0][t] + sps[1][t] + sps[2][t] + sps[3][t];
      dst1t[(size_t)(rb + t) * 4 + hd] = sds[0][t] + sds[1][t] + sds[2][t] + sds[3][t];
    }
  }
}

// ---- D2: attn1. One wave/row; 2-deep pipelined gather (16 loads in flight).
__global__ __launch_bounds__(256) void k_attn1(const u16b* __restrict__ mask,
    const u16b* __restrict__ Wh1bf,
    const float* __restrict__ src1t, const float* __restrict__ dst1t,
    const float* __restrict__ W2, const float* __restrict__ as2,
    const float* __restrict__ ad2, float* __restrict__ Wh2,
    float* __restrict__ src2, float* __restrict__ dst2) {
  int w = threadIdx.x >> 6, lane = threadIdx.x & 63;
  int n = blockIdx.x * 4 + w;
  __shared__ u16b lst4[4][512];
  __shared__ unsigned short ewh4[4][2048];     // f16 normalized weights [li*4+k]
  __shared__ float h1t4[4][512];               // transposed: [(col&7)*64 + col>>3]
  u16b* lst = lst4[w];
  unsigned short* ewh = ewh4[w];
  float* h1t = h1t4[w];
  // ---- decode: lane l owns cols [64l, 64l+64)
  unsigned long long B = *(const unsigned long long*)((const char*)mask + (size_t)n * 512 + lane * 8);
  int pc = __popcll(B);
  int incl = pc;
#pragma unroll
  for (int off = 1; off <= 32; off <<= 1) {
    int v = __shfl_up(incl, off);
    if (lane >= off) incl += v;
  }
  int cnt = __shfl(incl, 63);
  int pos = incl - pc;
  while (B) {
    int c = __builtin_ctzll(B);
    lst[pos++] = (u16b)(lane * 64 + c);
    B &= B - 1;
  }
  // ---- pad to even # of 8-edge chunks (weights 0 -> no effect)
  int nch = (cnt + 7) >> 3;
  int nch2 = nch + (nch & 1);
  for (int i = cnt + lane; i < nch2 * 8; i += 64) {
    lst[i] = 0;
    *(unsigned long long*)(&ewh[i * 4]) = 0ull;
  }
  // ---- logits all 4 heads, online softmax in registers
  floatx4 sn = *(const floatx4*)(src1t + (size_t)n * 4);
  float mx[4], sm[4];
#pragma unroll
  for (int k = 0; k < 4; ++k) { mx[k] = -1e30f; sm[k] = 0.f; }
  for (int li = lane; li < cnt; li += 64) {
    int m = lst[li];
    floatx4 dv = *(const floatx4*)(dst1t + (size_t)m * 4);
    ushortx4 ev;
#pragma unroll
    for (int k = 0; k < 4; ++k) {
      float e = sn[k] + dv[k];
      e = e > 0.f ? e : 0.2f * e;
      ev[k] = __half_as_ushort(__float2half(e));
      if (e > mx[k]) { sm[k] = sm[k] * __expf(mx[k] - e) + 1.f; mx[k] = e; }
      else sm[k] += __expf(e - mx[k]);
    }
    *(ushortx4*)(&ewh[li * 4]) = ev;
  }
#pragma unroll
  for (int k = 0; k < 4; ++k) {
#pragma unroll
    for (int off = 32; off >= 1; off >>= 1) {
      float mo = __shfl_xor(mx[k], off);
      float so = __shfl_xor(sm[k], off);
      float M = fmaxf(mx[k], mo);
      sm[k] = sm[k] * __expf(mx[k] - M) + so * __expf(mo - M);
      mx[k] = M;
    }
    sm[k] = 1.f / sm[k];
  }
  for (int li = lane; li < cnt; li += 64) {
    ushortx4 ev = *(const ushortx4*)(&ewh[li * 4]);
#pragma unroll
    for (int k = 0; k < 4; ++k) {
      float e = h2f(ev[k]);
      ev[k] = __half_as_ushort(__float2half(__expf(e - mx[k]) * sm[k]));
    }
    *(ushortx4*)(&ewh[li * 4]) = ev;
  }
  // ---- gather: 2-deep chunk pipeline. Chunk = 8 coalesced 1KB row reads.
  int hd = lane >> 4;
  const char* gb = (const char*)Wh1bf + lane * 16;
  float a[8] = {0.f, 0.f, 0.f, 0.f, 0.f, 0.f, 0.f, 0.f};
  int ma[8]; float wa[8]; uintx4 A[8];
#pragma unroll
  for (int q = 0; q < 8; ++q) { ma[q] = lst[q]; wa[q] = h2f(ewh[q * 4 + hd]); }
#pragma unroll
  for (int q = 0; q < 8; ++q) A[q] = *(const uintx4*)(gb + (size_t)ma[q] * 1024);
  for (int c = 0; c < nch2; c += 2) {
    // issue chunk c+1 into B (always exists: nch2 even)
    int mb[8]; float wb[8]; uintx4 Bv[8];
#pragma unroll
    for (int q = 0; q < 8; ++q) {
      int li = (c + 1) * 8 + q;
      mb[q] = lst[li]; wb[q] = h2f(ewh[li * 4 + hd]);
    }
#pragma unroll
    for (int q = 0; q < 8; ++q) Bv[q] = *(const uintx4*)(gb + (size_t)mb[q] * 1024);
    // consume A (waits vmcnt(8): B stays in flight)
#pragma unroll
    for (int q = 0; q < 8; ++q) {
      float f = wa[q];
#pragma unroll
      for (int j = 0; j < 4; ++j) {
        a[2*j]   = fmaf(f, bflo(A[q][j]), a[2*j]);
        a[2*j+1] = fmaf(f, bfhi(A[q][j]), a[2*j+1]);
      }
    }
    if (c + 2 < nch2) {
      // issue chunk c+2 into A
#pragma unroll
      for (int q = 0; q < 8; ++q) {
        int li = (c + 2) * 8 + q;
        ma[q] = lst[li]; wa[q] = h2f(ewh[li * 4 + hd]);
      }
#pragma unroll
      for (int q = 0; q < 8; ++q) A[q] = *(const uintx4*)(gb + (size_t)ma[q] * 1024);
    }
    // consume B
#pragma unroll
    for (int q = 0; q < 8; ++q) {
      float f = wb[q];
#pragma unroll
      for (int j = 0; j < 4; ++j) {
        a[2*j]   = fmaf(f, bflo(Bv[q][j]), a[2*j]);
        a[2*j+1] = fmaf(f, bfhi(Bv[q][j]), a[2*j+1]);
      }
    }
  }
  // ---- ELU + transposed store: col = 8*lane + j -> h1t[j*64 + lane]
#pragma unroll
  for (int j = 0; j < 8; ++j) {
    float v = a[j];
    h1t[j * 64 + lane] = v > 0.f ? v : __expf(v) - 1.f;
  }
  // ---- projection: out[o] = sum_i h1[i] W2[i][o]; h1[i] = h1t[(i&7)*64+(i>>3)]
  int o = lane & 15, ig = lane >> 4;
  float p0 = 0.f, p1 = 0.f, p2 = 0.f, p3 = 0.f;
  for (int j = 0; j < 128; j += 4) {
    int i0 = ig + 4 * j;
    int i1 = i0 + 4, i2 = i0 + 8, i3 = i0 + 12;
    p0 = fmaf(h1t[(i0 & 7) * 64 + (i0 >> 3)], W2[i0 * 16 + o], p0);
    p1 = fmaf(h1t[(i1 & 7) * 64 + (i1 >> 3)], W2[i1 * 16 + o], p1);
    p2 = fmaf(h1t[(i2 & 7) * 64 + (i2 >> 3)], W2[i2 * 16 + o], p2);
    p3 = fmaf(h1t[(i3 & 7) * 64 + (i3 >> 3)], W2[i3 * 16 + o], p3);
  }
  float pacc = (p0 + p1) + (p2 + p3);
  pacc += __shfl_xor(pacc, 16);
  pacc += __shfl_xor(pacc, 32);
  if (lane < 16) {
    Wh2[(size_t)n * 16 + lane] = pacc;
    float ps = pacc * as2[lane];
    float pd = pacc * ad2[lane];
#pragma unroll
    for (int off = 8; off >= 1; off >>= 1) {
      ps += __shfl_xor(ps, off, 16);
      pd += __shfl_xor(pd, off, 16);
    }
    if (lane == 0) { src2[n] = ps; dst2[n] = pd; }
  }
}

// ---- D3: fused decode+logits -> attn + log_softmax. One wave per row.
__global__ __launch_bounds__(256) void k_attn2(const u16b* __restrict__ mask,
    const float* __restrict__ Wh2, const float* __restrict__ src2,
    const float* __restrict__ dst2, float* __restrict__ out) {
  int w = threadIdx.x >> 6, lane = threadIdx.x & 63;
  int n = blockIdx.x * 4 + w;
  __shared__ int2 pr4[4][512];
  int2* pr = pr4[w];
  float snv = src2[n];
  unsigned long long B = *(const unsigned long long*)((const char*)mask + (size_t)n * 512 + lane * 8);
  int pc = __popcll(B);
  int incl = pc;
#pragma unroll
  for (int off = 1; off <= 32; off <<= 1) {
    int v = __shfl_up(incl, off);
    if (lane >= off) incl += v;
  }
  int cnt = __shfl(incl, 63);
  int pos = incl - pc;
  float mx = -1e30f, sm = 0.f;
  while (B) {
    int c = __builtin_ctzll(B);
    int m = lane * 64 + c;
    float e = snv + dst2[m];
    e = e > 0.f ? e : 0.2f * e;
    if (e > mx) { sm = sm * __expf(mx - e) + 1.f; mx = e; }
    else sm += __expf(e - mx);
    int2 pv; pv.x = m << 4; pv.y = __float_as_int(e);
    pr[pos++] = pv;
    B &= B - 1;
  }
#pragma unroll
  for (int off = 32; off >= 1; off >>= 1) {
    float mo = __shfl_xor(mx, off);
    float so = __shfl_xor(sm, off);
    float M = fmaxf(mx, mo);
    sm = sm * __expf(mx - M) + so * __expf(mo - M);
    mx = M;
  }
  float R = 1.f / sm;
  int o = lane & 15, g = lane >> 4;
  float acc = 0.f;
  for (int li = g; li < cnt; li += 4) {
    int2 pv = pr[li];
    float wgt = __expf(__int_as_float(pv.y) - mx) * R;
    acc = fmaf(wgt, Wh2[pv.x + o], acc);
  }
  acc += __shfl_xor(acc, 16);
  acc += __shfl_xor(acc, 32);
  float vm = acc;
#pragma unroll
  for (int off = 8; off >= 1; off >>= 1) vm = fmaxf(vm, __shfl_xor(vm, off, 16));
  float ex = __expf(acc - vm);
#pragma unroll
  for (int off = 8; off >= 1; off >>= 1) ex += __shfl_xor(ex, off, 16);
  if (lane < 16) out[(size_t)n * 16 + lane] = acc - vm - __logf(ex);
}

extern "C" void kernel_launch(void* const* d_in, const int* in_sizes, int n_in,
                              void* d_out, int out_size, void* d_ws, size_t ws_size,
                              hipStream_t stream) {
  const float* X   = (const float*)d_in[0];
  const float* adj = (const float*)d_in[1];
  const float* W1  = (const float*)d_in[2];
  const float* as1 = (const float*)d_in[3];
  const float* ad1 = (const float*)d_in[4];
  const float* W2  = (const float*)d_in[5];
  const float* as2 = (const float*)d_in[6];
  const float* ad2 = (const float*)d_in[7];
  float* out = (float*)d_out;

  char* ws = (char*)d_ws;
  float* src1t = (float*)ws;                         // 64 KB
  float* dst1t = (float*)(ws + (64 << 10));          // 64 KB
  float* src2  = (float*)(ws + (128 << 10));         // 16 KB
  float* dst2  = (float*)(ws + (144 << 10));         // 16 KB
  float* Wh2   = (float*)(ws + (160 << 10));         // 256 KB
  u16b*  mask  = (u16b*)(ws + (512 << 10));          // 2 MB
  u16b*  Wh1bf = (u16b*)(ws + (4ull << 20));         // 4 MB

  k_fused1<<<dim3(2304), dim3(512), 0, stream>>>(adj, X, W1, as1, ad1,
                                                 mask, Wh1bf, src1t, dst1t);
  k_attn1<<<dim3(1024), dim3(256), 0, stream>>>(mask, Wh1bf, src1t, dst1t,
                                                W2, as2, ad2, Wh2, src2, dst2);
  k_attn2<<<dim3(1024), dim3(256), 0, stream>>>(mask, Wh2, src2, dst2, out);
}

// Round 13
// 55.061 us; speedup vs baseline: 1.2809x; 1.0456x over previous
//
#include <hip/hip_runtime.h>
#include <hip/hip_bf16.h>
#include <hip/hip_fp16.h>

// GAT on MI355X. N=4096, DIN=512, H=128, K=4 heads, DOUT=16, p(adj)=0.01.
// D1 k_fused1: gemm1 (MFMA, blocks 0..255) || adj->bitmask (blocks 256..2303).
// D2 k_attn1:  one block per row, one wave per head (full occupancy):
//              per-wave decode -> head logits -> softmax -> dword/lane gather
//              (8-batched) -> ELU -> barrier -> per-head projection partials.
// D3 k_attn2:  fused decode+logits -> attn + log_softmax (one wave per row).

typedef __attribute__((ext_vector_type(4))) float floatx4;
typedef __attribute__((ext_vector_type(8))) short short8;
typedef __attribute__((ext_vector_type(4))) unsigned short ushortx4;
typedef unsigned short u16b;

#define GN 4096
#define LDP 40

__device__ __forceinline__ u16b f2bf(float f) {
  union { float f; unsigned int i; } v; v.f = f;
  unsigned int r = v.i + 0x7FFF + ((v.i >> 16) & 1);
  return (u16b)(r >> 16);
}
__device__ __forceinline__ float bflo(unsigned u) {
  union { unsigned i; float f; } v; v.i = u << 16; return v.f;
}
__device__ __forceinline__ float bfhi(unsigned u) {
  union { unsigned i; float f; } v; v.i = u & 0xffff0000u; return v.f;
}
__device__ __forceinline__ float h2f(unsigned short h) {
  return __half2float(__ushort_as_half(h));
}

// ---- D1: gemm1 (blocks 0..255) || bitmask build (blocks 256..2303). (unchanged)
__global__ __launch_bounds__(512) void k_fused1(const float* __restrict__ adj,
    const float* __restrict__ X, const float* __restrict__ W1,
    const float* __restrict__ as1, const float* __restrict__ ad1,
    u16b* __restrict__ mask, u16b* __restrict__ Wh1bf,
    float* __restrict__ src1t, float* __restrict__ dst1t) {
  int b = blockIdx.x, t = threadIdx.x;
  int lane = t & 63, w = t >> 6;
  if (b >= 256) {
    int n = (b - 256) * 2 + (t >> 8);
    int cg = t & 255;
    const float* ap = adj + (size_t)n * 4096 + cg * 16;
    floatx4 v0 = *(const floatx4*)(ap);
    floatx4 v1 = *(const floatx4*)(ap + 4);
    floatx4 v2 = *(const floatx4*)(ap + 8);
    floatx4 v3 = *(const floatx4*)(ap + 12);
    unsigned bits = 0;
#pragma unroll
    for (int i = 0; i < 4; ++i) {
      bits |= (unsigned)(v0[i] != 0.f) << i;
      bits |= (unsigned)(v1[i] != 0.f) << (4 + i);
      bits |= (unsigned)(v2[i] != 0.f) << (8 + i);
      bits |= (unsigned)(v3[i] != 0.f) << (12 + i);
    }
    if ((n >> 4) == cg) bits |= 1u << (n & 15);
    mask[(size_t)n * 256 + cg] = (u16b)bits;
  } else {
    __shared__ u16b Ab[64 * LDP];
    __shared__ u16b Bb[128 * LDP];
    __shared__ float sps[4][64], sds[4][64];
    int p = ((b >> 5) << 3) | (b & 7);
    int hd = (b >> 3) & 3;
    int rb = p * 64;
    const float* Wk = W1 + (size_t)hd * 65536;
    int wr = w >> 2, wc = w & 3, lh = lane >> 4, lm = lane & 15;
    int ar = t >> 2, aq = t & 3;
    int u = t - 256, kk0 = (u & 7) * 4, c0 = (u >> 3) * 4;
    floatx4 pa0, pa1, pb0, pb1, pb2, pb3;
    if (t < 256) {
      const float* ap = X + (size_t)(rb + ar) * 512 + aq * 8;
      pa0 = *(const floatx4*)(ap);
      pa1 = *(const floatx4*)(ap + 4);
    } else {
      const float* bp = Wk + (size_t)kk0 * 128 + c0;
      pb0 = *(const floatx4*)(bp);
      pb1 = *(const floatx4*)(bp + 128);
      pb2 = *(const floatx4*)(bp + 256);
      pb3 = *(const floatx4*)(bp + 384);
    }
    floatx4 acc[2][2] = {};
    for (int kk = 0; kk < 512; kk += 32) {
      if (t < 256) {
        short8 a;
        a[0] = (short)f2bf(pa0[0]); a[1] = (short)f2bf(pa0[1]);
        a[2] = (short)f2bf(pa0[2]); a[3] = (short)f2bf(pa0[3]);
        a[4] = (short)f2bf(pa1[0]); a[5] = (short)f2bf(pa1[1]);
        a[6] = (short)f2bf(pa1[2]); a[7] = (short)f2bf(pa1[3]);
        *(short8*)(&Ab[ar * LDP + aq * 8]) = a;
      } else {
#pragma unroll
        for (int cq = 0; cq < 4; ++cq) {
          ushortx4 v;
          v[0] = f2bf(pb0[cq]); v[1] = f2bf(pb1[cq]);
          v[2] = f2bf(pb2[cq]); v[3] = f2bf(pb3[cq]);
          *(ushortx4*)(&Bb[(c0 + cq) * LDP + kk0]) = v;
        }
      }
      __syncthreads();
      if (kk + 32 < 512) {
        if (t < 256) {
          const float* ap = X + (size_t)(rb + ar) * 512 + kk + 32 + aq * 8;
          pa0 = *(const floatx4*)(ap);
          pa1 = *(const floatx4*)(ap + 4);
        } else {
          const float* bp = Wk + (size_t)(kk + 32 + kk0) * 128 + c0;
          pb0 = *(const floatx4*)(bp);
          pb1 = *(const floatx4*)(bp + 128);
          pb2 = *(const floatx4*)(bp + 256);
          pb3 = *(const floatx4*)(bp + 384);
        }
      }
      short8 a0 = *(const short8*)(&Ab[(wr * 32      + lm) * LDP + lh * 8]);
      short8 a1 = *(const short8*)(&Ab[(wr * 32 + 16 + lm) * LDP + lh * 8]);
      short8 b0 = *(const short8*)(&Bb[(wc * 32      + lm) * LDP + lh * 8]);
      short8 b1 = *(const short8*)(&Bb[(wc * 32 + 16 + lm) * LDP + lh * 8]);
      acc[0][0] = __builtin_amdgcn_mfma_f32_16x16x32_bf16(a0, b0, acc[0][0], 0, 0, 0);
      acc[0][1] = __builtin_amdgcn_mfma_f32_16x16x32_bf16(a0, b1, acc[0][1], 0, 0, 0);
      acc[1][0] = __builtin_amdgcn_mfma_f32_16x16x32_bf16(a1, b0, acc[1][0], 0, 0, 0);
      acc[1][1] = __builtin_amdgcn_mfma_f32_16x16x32_bf16(a1, b1, acc[1][1], 0, 0, 0);
      __syncthreads();
    }
#pragma unroll
    for (int m = 0; m < 2; ++m)
#pragma unroll
      for (int n2 = 0; n2 < 2; ++n2)
#pragma unroll
        for (int j = 0; j < 4; ++j)
          Wh1bf[(size_t)(rb + wr * 32 + m * 16 + lh * 4 + j) * 512
                + hd * 128 + wc * 32 + n2 * 16 + lm] = f2bf(acc[m][n2][j]);
    float asv[2], adv[2];
#pragma unroll
    for (int n2 = 0; n2 < 2; ++n2) {
      asv[n2] = as1[hd * 128 + wc * 32 + n2 * 16 + lm];
      adv[n2] = ad1[hd * 128 + wc * 32 + n2 * 16 + lm];
    }
#pragma unroll
    for (int m = 0; m < 2; ++m)
#pragma unroll
      for (int j = 0; j < 4; ++j) {
        float ps = acc[m][0][j] * asv[0] + acc[m][1][j] * asv[1];
        float pd = acc[m][0][j] * adv[0] + acc[m][1][j] * adv[1];
#pragma unroll
        for (int off = 8; off >= 1; off >>= 1) {
          ps += __shfl_xor(ps, off, 16);
          pd += __shfl_xor(pd, off, 16);
        }
        if (lm == 0) {
          sps[wc][wr * 32 + m * 16 + lh * 4 + j] = ps;
          sds[wc][wr * 32 + m * 16 + lh * 4 + j] = pd;
        }
      }
    __syncthreads();
    if (t < 64) {
      src1t[(size_t)(rb + t) * 4 + hd] = sps[0][t] + sps[1][t] + sps[2][t] + sps[3][t];
      dst1t[(size_t)(rb + t) * 4 + hd] = sds[0][t] + sds[1][t] + sds[2][t] + sds[3][t];
    }
  }
}

// ---- D2: attn1. One block per row, one wave per head. Full occupancy.
__global__ __launch_bounds__(256, 8) void k_attn1(const u16b* __restrict__ mask,
    const u16b* __restrict__ Wh1bf,
    const float* __restrict__ src1t, const float* __restrict__ dst1t,
    const float* __restrict__ W2, const float* __restrict__ as2,
    const float* __restrict__ ad2, float* __restrict__ Wh2,
    float* __restrict__ src2, float* __restrict__ dst2) {
  int w = threadIdx.x >> 6, lane = threadIdx.x & 63;
  int n = blockIdx.x;
  __shared__ u16b lst[512];
  __shared__ unsigned short ewh[4][512];   // f16 normalized weights per head
  __shared__ float h1row[512];
  __shared__ float redw[4][16];
  // ---- decode (each wave redundantly; identical values -> benign)
  unsigned long long B = *(const unsigned long long*)((const char*)mask + (size_t)n * 512 + lane * 8);
  int pc = __popcll(B);
  int incl = pc;
#pragma unroll
  for (int off = 1; off <= 32; off <<= 1) {
    int v = __shfl_up(incl, off);
    if (lane >= off) incl += v;
  }
  int cnt = __shfl(incl, 63);
  int pos = incl - pc;
  while (B) {
    int c = __builtin_ctzll(B);
    lst[pos++] = (u16b)(lane * 64 + c);
    B &= B - 1;
  }
  // ---- pad own head's weights to chunk boundary (zero weight = no effect)
  int nch = (cnt + 7) >> 3;
  for (int i = cnt + lane; i < nch * 8; i += 64) { lst[i] = 0; ewh[w][i] = 0; }
  // ---- head-w logits + online softmax (cnt<64 -> ~1 edge per lane)
  float snw = src1t[(size_t)n * 4 + w];
  float mx = -1e30f, sm = 0.f;
  for (int li = lane; li < cnt; li += 64) {
    int m = lst[li];
    float e = snw + dst1t[(size_t)m * 4 + w];
    e = e > 0.f ? e : 0.2f * e;
    ewh[w][li] = __half_as_ushort(__float2half(e));
    if (e > mx) { sm = sm * __expf(mx - e) + 1.f; mx = e; }
    else sm += __expf(e - mx);
  }
#pragma unroll
  for (int off = 32; off >= 1; off >>= 1) {
    float mo = __shfl_xor(mx, off);
    float so = __shfl_xor(sm, off);
    float M = fmaxf(mx, mo);
    sm = sm * __expf(mx - M) + so * __expf(mo - M);
    mx = M;
  }
  float R = 1.f / sm;
  for (int li = lane; li < cnt; li += 64) {
    float e = h2f(ewh[w][li]);
    ewh[w][li] = __half_as_ushort(__float2half(__expf(e - mx) * R));
  }
  // ---- gather: lane owns 2 cols of head w; 1 dword per edge, 8-batched.
  const char* gb = (const char*)Wh1bf + w * 256 + lane * 4;
  float a0 = 0.f, a1 = 0.f;
  for (int c = 0; c < nch; ++c) {
    int mreg[8]; float wreg[8]; unsigned ureg[8];
#pragma unroll
    for (int q = 0; q < 8; ++q) {
      int li = c * 8 + q;
      mreg[q] = lst[li];
      wreg[q] = h2f(ewh[w][li]);
    }
#pragma unroll
    for (int q = 0; q < 8; ++q)
      ureg[q] = *(const unsigned*)(gb + (size_t)mreg[q] * 1024);
#pragma unroll
    for (int q = 0; q < 8; ++q) {
      a0 = fmaf(wreg[q], bflo(ureg[q]), a0);
      a1 = fmaf(wreg[q], bfhi(ureg[q]), a1);
    }
  }
  // ---- ELU -> h1row
  a0 = a0 > 0.f ? a0 : __expf(a0) - 1.f;
  a1 = a1 > 0.f ? a1 : __expf(a1) - 1.f;
  h1row[w * 128 + lane * 2]     = a0;
  h1row[w * 128 + lane * 2 + 1] = a1;
  __syncthreads();
  // ---- fused layer-2 projection: wave w covers ONLY i in [w*128,(w+1)*128)
  {
    int o = lane & 15, ig = lane >> 4;
    int base = w * 128 + ig;
    float p0 = 0.f, p1 = 0.f, p2 = 0.f, p3 = 0.f;
#pragma unroll
    for (int m = 0; m < 32; m += 4) {
      int i0 = base + 4 * m;
      p0 = fmaf(h1row[i0],      W2[i0 * 16 + o],        p0);
      p1 = fmaf(h1row[i0 + 4],  W2[(i0 + 4) * 16 + o],  p1);
      p2 = fmaf(h1row[i0 + 8],  W2[(i0 + 8) * 16 + o],  p2);
      p3 = fmaf(h1row[i0 + 12], W2[(i0 + 12) * 16 + o], p3);
    }
    float pacc = (p0 + p1) + (p2 + p3);
    pacc += __shfl_xor(pacc, 16);
    pacc += __shfl_xor(pacc, 32);
    if (lane < 16) redw[w][lane] = pacc;
  }
  __syncthreads();
  if (threadIdx.x < 16) {
    int t = threadIdx.x;
    float v = redw[0][t] + redw[1][t] + redw[2][t] + redw[3][t];
    Wh2[(size_t)n * 16 + t] = v;
    float ps = v * as2[t];
    float pd = v * ad2[t];
#pragma unroll
    for (int off = 8; off >= 1; off >>= 1) {
      ps += __shfl_xor(ps, off, 16);
      pd += __shfl_xor(pd, off, 16);
    }
    if (t == 0) { src2[n] = ps; dst2[n] = pd; }
  }
}

// ---- D3: fused decode+logits -> attn + log_softmax. One wave per row. (unchanged)
__global__ __launch_bounds__(256) void k_attn2(const u16b* __restrict__ mask,
    const float* __restrict__ Wh2, const float* __restrict__ src2,
    const float* __restrict__ dst2, float* __restrict__ out) {
  int w = threadIdx.x >> 6, lane = threadIdx.x & 63;
  int n = blockIdx.x * 4 + w;
  __shared__ int2 pr4[4][512];
  int2* pr = pr4[w];
  float snv = src2[n];
  unsigned long long B = *(const unsigned long long*)((const char*)mask + (size_t)n * 512 + lane * 8);
  int pc = __popcll(B);
  int incl = pc;
#pragma unroll
  for (int off = 1; off <= 32; off <<= 1) {
    int v = __shfl_up(incl, off);
    if (lane >= off) incl += v;
  }
  int cnt = __shfl(incl, 63);
  int pos = incl - pc;
  float mx = -1e30f, sm = 0.f;
  while (B) {
    int c = __builtin_ctzll(B);
    int m = lane * 64 + c;
    float e = snv + dst2[m];
    e = e > 0.f ? e : 0.2f * e;
    if (e > mx) { sm = sm * __expf(mx - e) + 1.f; mx = e; }
    else sm += __expf(e - mx);
    int2 pv; pv.x = m << 4; pv.y = __float_as_int(e);
    pr[pos++] = pv;
    B &= B - 1;
  }
#pragma unroll
  for (int off = 32; off >= 1; off >>= 1) {
    float mo = __shfl_xor(mx, off);
    float so = __shfl_xor(sm, off);
    float M = fmaxf(mx, mo);
    sm = sm * __expf(mx - M) + so * __expf(mo - M);
    mx = M;
  }
  float R = 1.f / sm;
  int o = lane & 15, g = lane >> 4;
  float acc = 0.f;
  for (int li = g; li < cnt; li += 4) {
    int2 pv = pr[li];
    float wgt = __expf(__int_as_float(pv.y) - mx) * R;
    acc = fmaf(wgt, Wh2[pv.x + o], acc);
  }
  acc += __shfl_xor(acc, 16);
  acc += __shfl_xor(acc, 32);
  float vm = acc;
#pragma unroll
  for (int off = 8; off >= 1; off >>= 1) vm = fmaxf(vm, __shfl_xor(vm, off, 16));
  float ex = __expf(acc - vm);
#pragma unroll
  for (int off = 8; off >= 1; off >>= 1) ex += __shfl_xor(ex, off, 16);
  if (lane < 16) out[(size_t)n * 16 + lane] = acc - vm - __logf(ex);
}

extern "C" void kernel_launch(void* const* d_in, const int* in_sizes, int n_in,
                              void* d_out, int out_size, void* d_ws, size_t ws_size,
                              hipStream_t stream) {
  const float* X   = (const float*)d_in[0];
  const float* adj = (const float*)d_in[1];
  const float* W1  = (const float*)d_in[2];
  const float* as1 = (const float*)d_in[3];
  const float* ad1 = (const float*)d_in[4];
  const float* W2  = (const float*)d_in[5];
  const float* as2 = (const float*)d_in[6];
  const float* ad2 = (const float*)d_in[7];
  float* out = (float*)d_out;

  char* ws = (char*)d_ws;
  float* src1t = (float*)ws;                         // 64 KB
  float* dst1t = (float*)(ws + (64 << 10));          // 64 KB
  float* src2  = (float*)(ws + (128 << 10));         // 16 KB
  float* dst2  = (float*)(ws + (144 << 10));         // 16 KB
  float* Wh2   = (float*)(ws + (160 << 10));         // 256 KB
  u16b*  mask  = (u16b*)(ws + (512 << 10));          // 2 MB
  u16b*  Wh1bf = (u16b*)(ws + (4ull << 20));         // 4 MB

  k_fused1<<<dim3(2304), dim3(512), 0, stream>>>(adj, X, W1, as1, ad1,
                                                 mask, Wh1bf, src1t, dst1t);
  k_attn1<<<dim3(GN), dim3(256), 0, stream>>>(mask, Wh1bf, src1t, dst1t,
                                              W2, as2, ad2, Wh2, src2, dst2);
  k_attn2<<<dim3(1024), dim3(256), 0, stream>>>(mask, Wh2, src2, dst2, out);
}